// Round 1
// baseline (3606.074 us; speedup 1.0000x reference)
//
#include <hip/hip_runtime.h>
#include <hip/hip_bf16.h>
#include <cstddef>

// Problem constants
#define BB 32
#define PP 196
#define DENC 256
#define EE 512
#define HH 512
#define AA 256
#define VV 30000
#define TT 20
#define BH (BB*HH)          // 16384
#define G4 (4*HH)           // 2048

__device__ __forceinline__ float fast_sigmoid(float x) {
    return 1.f / (1.f + __expf(-x));
}
__device__ __forceinline__ float fast_tanh(float x) {
    x = fminf(fmaxf(x, -15.f), 15.f);
    float e = __expf(2.f * x);
    return (e - 1.f) / (e + 1.f);
}

// ---------------------------------------------------------------------------
// att1[b,p,a] = enc[b,p,:] @ W_enc_att[:,a] + b_enc_att[a]
// 8 rows per block, 256 threads (one per output col a)
// ---------------------------------------------------------------------------
__global__ void att1_kernel(const float* __restrict__ enc,
                            const float* __restrict__ W,
                            const float* __restrict__ bias,
                            float* __restrict__ att1) {
    __shared__ float xs[8][DENC];
    const int tid = threadIdx.x;
    const int r0 = blockIdx.x * 8;
    #pragma unroll
    for (int bi = 0; bi < 8; ++bi)
        xs[bi][tid] = enc[(size_t)(r0 + bi) * DENC + tid];
    __syncthreads();
    float acc[8];
    const float bv = bias[tid];
    #pragma unroll
    for (int bi = 0; bi < 8; ++bi) acc[bi] = bv;
    #pragma unroll 4
    for (int k = 0; k < DENC; ++k) {
        const float w = W[k * AA + tid];
        #pragma unroll
        for (int bi = 0; bi < 8; ++bi) acc[bi] += xs[bi][k] * w;
    }
    #pragma unroll
    for (int bi = 0; bi < 8; ++bi)
        att1[(size_t)(r0 + bi) * AA + tid] = acc[bi];
}

// ---------------------------------------------------------------------------
// Per-timestep attention kernel. One block per batch element (32 blocks, 256 thr).
// Phase 0: LSTM pointwise update for step t-1 (or zero-init at t=0)
// Phase 1: att2 = h @ W_dec_att + b_dec_att
// Phase 2: e[p] = tanh(att1[p,:]+att2) @ W_full + b_full   (wave-per-p reduce)
// Phase 3: softmax over p
// Phase 4: context[d] = sum_p alpha[p]*enc[b,p,d]
// ---------------------------------------------------------------------------
__global__ void attn_step_kernel(int t,
                                 const float* __restrict__ att1,
                                 const float* __restrict__ enc,
                                 float* __restrict__ Hall,
                                 float* __restrict__ cbuf,
                                 const float* __restrict__ gates,
                                 float* __restrict__ context,
                                 const float* __restrict__ Wda,
                                 const float* __restrict__ bda,
                                 const float* __restrict__ Wfull,
                                 const float* __restrict__ bfull) {
    __shared__ float h_s[HH];
    __shared__ float att2_s[AA];
    __shared__ float e_s[256];
    __shared__ float red_s[256];
    const int b = blockIdx.x;
    const int tid = threadIdx.x;

    // Phase 0: finish LSTM cell of step t-1 (h_{t-1}), or init h=c=0
    if (t == 0) {
        h_s[tid] = 0.f; h_s[tid + 256] = 0.f;
        cbuf[b * HH + tid] = 0.f; cbuf[b * HH + tid + 256] = 0.f;
    } else {
        const float* g = gates + b * G4;
        #pragma unroll
        for (int q = 0; q < 2; ++q) {
            const int hi = tid + q * 256;
            const float gi = g[hi];
            const float gf = g[HH + hi];
            const float gg = g[2 * HH + hi];
            const float go = g[3 * HH + hi];
            const float cp = cbuf[b * HH + hi];
            const float cn = fast_sigmoid(gf) * cp + fast_sigmoid(gi) * fast_tanh(gg);
            const float hn = fast_sigmoid(go) * fast_tanh(cn);
            cbuf[b * HH + hi] = cn;
            Hall[(size_t)(t - 1) * BH + b * HH + hi] = hn;
            h_s[hi] = hn;
        }
    }
    __syncthreads();

    // Phase 1: att2 (256 outputs, one per thread)
    {
        float acc = bda[tid];
        #pragma unroll 4
        for (int k = 0; k < HH; ++k) acc += h_s[k] * Wda[k * AA + tid];
        att2_s[tid] = acc;
    }
    __syncthreads();

    // Phase 2: e[p], one wave per p (4 waves round-robin over 196 p's)
    {
        const int wave = tid >> 6, lane = tid & 63;
        for (int p = wave; p < PP; p += 4) {
            const float* row = att1 + ((size_t)b * PP + p) * AA;
            float s = 0.f;
            #pragma unroll
            for (int q = 0; q < 4; ++q) {
                const int a = lane + q * 64;
                s += fast_tanh(row[a] + att2_s[a]) * Wfull[a];
            }
            #pragma unroll
            for (int off = 32; off > 0; off >>= 1) s += __shfl_down(s, off, 64);
            if (lane == 0) e_s[p] = s + bfull[0];
        }
    }
    __syncthreads();

    // Phase 3: softmax over the 196 e's
    const float val = (tid < PP) ? e_s[tid] : -3.4e38f;
    red_s[tid] = val;
    __syncthreads();
    #pragma unroll
    for (int s = 128; s > 0; s >>= 1) {
        if (tid < s) red_s[tid] = fmaxf(red_s[tid], red_s[tid + s]);
        __syncthreads();
    }
    const float mx = red_s[0];
    __syncthreads();
    const float ex = (tid < PP) ? __expf(val - mx) : 0.f;
    red_s[tid] = ex;
    __syncthreads();
    #pragma unroll
    for (int s = 128; s > 0; s >>= 1) {
        if (tid < s) red_s[tid] += red_s[tid + s];
        __syncthreads();
    }
    const float inv = 1.f / red_s[0];
    __syncthreads();
    e_s[tid] = ex * inv;        // alpha (0 for tid>=196)
    __syncthreads();

    // Phase 4: context
    {
        float acc = 0.f;
        const float* erow = enc + (size_t)b * PP * DENC + tid;
        #pragma unroll 4
        for (int p = 0; p < PP; ++p) acc += e_s[p] * erow[(size_t)p * DENC];
        context[b * DENC + tid] = acc;
    }
}

// ---------------------------------------------------------------------------
// gates[b, j] = x @ W_ih + b_ih + h @ W_hh + b_hh
// x = [emb[cap], context], K = 768 (+512 for h)
// grid (8 j-chunks, 8 batch-groups), 256 threads; 4 batches per thread.
// ---------------------------------------------------------------------------
__global__ void gates_kernel(int t,
                             const int* __restrict__ captions,
                             const float* __restrict__ emb,
                             const float* __restrict__ context,
                             const float* __restrict__ Hall,
                             const float* __restrict__ Wih,
                             const float* __restrict__ bih,
                             const float* __restrict__ Whh,
                             const float* __restrict__ bhh,
                             float* __restrict__ gates) {
    __shared__ float x_s[4][1280];
    const int tid = threadIdx.x;
    const int jc = blockIdx.x;       // 0..7
    const int bg = blockIdx.y;       // 0..7
    const int j = jc * 256 + tid;

    #pragma unroll
    for (int bi = 0; bi < 4; ++bi) {
        const int b = bg * 4 + bi;
        const int cap = captions[b * TT + t];
        const float* erow = emb + (size_t)cap * EE;
        x_s[bi][tid]       = erow[tid];
        x_s[bi][tid + 256] = erow[tid + 256];
        x_s[bi][512 + tid] = context[b * DENC + tid];
        if (t > 0) {
            const float* hp = Hall + (size_t)(t - 1) * BH + b * HH;
            x_s[bi][768 + tid]  = hp[tid];
            x_s[bi][1024 + tid] = hp[tid + 256];
        } else {
            x_s[bi][768 + tid] = 0.f;
            x_s[bi][1024 + tid] = 0.f;
        }
    }
    __syncthreads();

    const float bb = bih[j] + bhh[j];
    float acc0 = bb, acc1 = bb, acc2 = bb, acc3 = bb;
    #pragma unroll 4
    for (int k = 0; k < 768; ++k) {
        const float w = Wih[(size_t)k * G4 + j];
        acc0 += x_s[0][k] * w;
        acc1 += x_s[1][k] * w;
        acc2 += x_s[2][k] * w;
        acc3 += x_s[3][k] * w;
    }
    #pragma unroll 4
    for (int k = 0; k < 512; ++k) {
        const float w = Whh[(size_t)k * G4 + j];
        acc0 += x_s[0][768 + k] * w;
        acc1 += x_s[1][768 + k] * w;
        acc2 += x_s[2][768 + k] * w;
        acc3 += x_s[3][768 + k] * w;
    }
    gates[(size_t)(bg * 4 + 0) * G4 + j] = acc0;
    gates[(size_t)(bg * 4 + 1) * G4 + j] = acc1;
    gates[(size_t)(bg * 4 + 2) * G4 + j] = acc2;
    gates[(size_t)(bg * 4 + 3) * G4 + j] = acc3;
}

// ---------------------------------------------------------------------------
// LSTM pointwise update for the final step (t = T-1) -> Hall[T-1]
// ---------------------------------------------------------------------------
__global__ void final_update_kernel(const float* __restrict__ gates,
                                    const float* __restrict__ cbuf,
                                    float* __restrict__ Hall) {
    const int idx = blockIdx.x * 256 + threadIdx.x;   // < 16384
    const int b = idx >> 9, hi = idx & 511;
    const float* g = gates + b * G4;
    const float gi = g[hi];
    const float gf = g[HH + hi];
    const float gg = g[2 * HH + hi];
    const float go = g[3 * HH + hi];
    const float cp = cbuf[idx];
    const float cn = fast_sigmoid(gf) * cp + fast_sigmoid(gi) * fast_tanh(gg);
    const float hn = fast_sigmoid(go) * fast_tanh(cn);
    Hall[(size_t)(TT - 1) * BH + idx] = hn;
}

// ---------------------------------------------------------------------------
// Output projection: C[m, v] = Hall_flat[m,:] @ W_fc[:,v] + b_fc[v]
// m = t*32 + b (Hall is [T][B][H] contiguous), written to out[b][t][v].
// Tiled fp32 GEMM: BM=64, BN=64, BK=16, 256 threads, 4x4 micro-tile.
// ---------------------------------------------------------------------------
#define BM 64
#define BN 64
#define BK 16

__global__ void gemm_out(const float* __restrict__ Hall,
                         const float* __restrict__ Wfc,
                         const float* __restrict__ bfc,
                         float* __restrict__ out) {
    __shared__ float As[BM][BK + 1];
    __shared__ float Bs[BK][BN];
    const int tid = threadIdx.x;
    const int tx = tid & 15, ty = tid >> 4;
    const int m0 = blockIdx.y * BM;
    const int v0 = blockIdx.x * BN;

    const int ar = tid >> 2, akq = (tid & 3) * 4;     // A-tile load coords
    const int bkr = tid >> 4, bvq = (tid & 15) * 4;   // B-tile load coords

    float acc[4][4] = {};

    for (int k0 = 0; k0 < HH; k0 += BK) {
        const float4 av = *reinterpret_cast<const float4*>(
            &Hall[(size_t)(m0 + ar) * HH + k0 + akq]);
        As[ar][akq + 0] = av.x; As[ar][akq + 1] = av.y;
        As[ar][akq + 2] = av.z; As[ar][akq + 3] = av.w;

        const int vcol = v0 + bvq;
        float4 bv = {0.f, 0.f, 0.f, 0.f};
        if (vcol < VV)
            bv = *reinterpret_cast<const float4*>(&Wfc[(size_t)(k0 + bkr) * VV + vcol]);
        Bs[bkr][bvq + 0] = bv.x; Bs[bkr][bvq + 1] = bv.y;
        Bs[bkr][bvq + 2] = bv.z; Bs[bkr][bvq + 3] = bv.w;
        __syncthreads();

        #pragma unroll
        for (int kk = 0; kk < BK; ++kk) {
            float a[4], bq[4];
            #pragma unroll
            for (int i = 0; i < 4; ++i) a[i] = As[ty * 4 + i][kk];
            #pragma unroll
            for (int jj = 0; jj < 4; ++jj) bq[jj] = Bs[kk][tx * 4 + jj];
            #pragma unroll
            for (int i = 0; i < 4; ++i)
                #pragma unroll
                for (int jj = 0; jj < 4; ++jj)
                    acc[i][jj] += a[i] * bq[jj];
        }
        __syncthreads();
    }

    #pragma unroll
    for (int i = 0; i < 4; ++i) {
        const int m = m0 + ty * 4 + i;
        const int t_idx = m >> 5;
        const int b_idx = m & 31;
        float* orow = out + ((size_t)b_idx * TT + t_idx) * VV;
        #pragma unroll
        for (int jj = 0; jj < 4; ++jj) {
            const int v = v0 + tx * 4 + jj;
            if (v < VV) orow[v] = acc[i][jj] + bfc[v];
        }
    }
}

// ---------------------------------------------------------------------------
extern "C" void kernel_launch(void* const* d_in, const int* in_sizes, int n_in,
                              void* d_out, int out_size, void* d_ws, size_t ws_size,
                              hipStream_t stream) {
    const float* enc      = (const float*)d_in[0];
    const int*   captions = (const int*)  d_in[1];
    const float* Wea      = (const float*)d_in[2];
    const float* bea      = (const float*)d_in[3];
    const float* Wda      = (const float*)d_in[4];
    const float* bda      = (const float*)d_in[5];
    const float* Wfull    = (const float*)d_in[6];
    const float* bfull    = (const float*)d_in[7];
    const float* emb      = (const float*)d_in[8];
    const float* Wih      = (const float*)d_in[9];
    const float* bih      = (const float*)d_in[10];
    const float* Whh      = (const float*)d_in[11];
    const float* bhh      = (const float*)d_in[12];
    const float* Wfc      = (const float*)d_in[13];
    const float* bfc      = (const float*)d_in[14];
    float* out = (float*)d_out;

    float* ws      = (float*)d_ws;
    float* att1    = ws;                        // 32*196*256     = 1,605,632
    float* Hall    = att1 + 1605632;            // 20*32*512      =   327,680
    float* cbuf    = Hall + 327680;             // 32*512         =    16,384
    float* context = cbuf + 16384;              // 32*256         =     8,192
    float* gates   = context + 8192;            // 32*2048        =    65,536

    att1_kernel<<<dim3(784), dim3(256), 0, stream>>>(enc, Wea, bea, att1);

    for (int t = 0; t < TT; ++t) {
        attn_step_kernel<<<dim3(BB), dim3(256), 0, stream>>>(
            t, att1, enc, Hall, cbuf, gates, context, Wda, bda, Wfull, bfull);
        gates_kernel<<<dim3(8, 8), dim3(256), 0, stream>>>(
            t, captions, emb, context, Hall, Wih, bih, Whh, bhh, gates);
    }
    final_update_kernel<<<dim3(64), dim3(256), 0, stream>>>(gates, cbuf, Hall);

    gemm_out<<<dim3((VV + BN - 1) / BN, (TT * BB) / BM), dim3(256), 0, stream>>>(
        Hall, Wfc, bfc, out);
}

// Round 2
// 1559.980 us; speedup vs baseline: 2.3116x; 2.3116x over previous
//
#include <hip/hip_runtime.h>
#include <hip/hip_bf16.h>
#include <cstddef>

// Problem constants
#define BB 32
#define PP 196
#define DENC 256
#define EE 512
#define HH 512
#define AA 256
#define VV 30000
#define TT 20
#define BH (BB*HH)          // 16384
#define G4 (4*HH)           // 2048

__device__ __forceinline__ float fast_sigmoid(float x) {
    return 1.f / (1.f + __expf(-x));
}
__device__ __forceinline__ float fast_tanh(float x) {
    x = fminf(fmaxf(x, -15.f), 15.f);
    float e = __expf(2.f * x);
    return (e - 1.f) / (e + 1.f);
}

// ---------------------------------------------------------------------------
// att1[b,p,a] = enc[b,p,:] @ W_enc_att[:,a] + b_enc_att[a]
// 8 rows per block, 256 threads (one per output col a)
// ---------------------------------------------------------------------------
__global__ void att1_kernel(const float* __restrict__ enc,
                            const float* __restrict__ W,
                            const float* __restrict__ bias,
                            float* __restrict__ att1) {
    __shared__ float xs[8][DENC];
    const int tid = threadIdx.x;
    const int r0 = blockIdx.x * 8;
    #pragma unroll
    for (int bi = 0; bi < 8; ++bi)
        xs[bi][tid] = enc[(size_t)(r0 + bi) * DENC + tid];
    __syncthreads();
    float acc[8];
    const float bv = bias[tid];
    #pragma unroll
    for (int bi = 0; bi < 8; ++bi) acc[bi] = bv;
    #pragma unroll 8
    for (int k = 0; k < DENC; ++k) {
        const float w = W[k * AA + tid];
        #pragma unroll
        for (int bi = 0; bi < 8; ++bi) acc[bi] += xs[bi][k] * w;
    }
    #pragma unroll
    for (int bi = 0; bi < 8; ++bi)
        att1[(size_t)(r0 + bi) * AA + tid] = acc[bi];
}

// ---------------------------------------------------------------------------
// Epre[m, j] = emb[captions[b,t]] @ W_ih[0:512, j] + b_ih[j] + b_hh[j]
// m = t*32 + b. Grid (8 j-chunks, 80 row-groups), 256 threads, 8 rows/block.
// Hoists the embedding half of the per-step gates GEMM out of the loop.
// ---------------------------------------------------------------------------
__global__ void epre_kernel(const int* __restrict__ captions,
                            const float* __restrict__ emb,
                            const float* __restrict__ Wih,
                            const float* __restrict__ bih,
                            const float* __restrict__ bhh,
                            float* __restrict__ Epre) {
    __shared__ float xs[8][EE];
    const int tid = threadIdx.x;
    const int jc = blockIdx.x;     // 0..7
    const int mg = blockIdx.y;     // 0..79
    const int j = jc * 256 + tid;

    #pragma unroll
    for (int i = 0; i < 8; ++i) {
        const int m = mg * 8 + i;
        const int t = m >> 5, b = m & 31;
        const int cap = captions[b * TT + t];
        const float* erow = emb + (size_t)cap * EE;
        xs[i][tid]       = erow[tid];
        xs[i][tid + 256] = erow[tid + 256];
    }
    __syncthreads();

    float acc[8];
    const float bv = bih[j] + bhh[j];
    #pragma unroll
    for (int i = 0; i < 8; ++i) acc[i] = bv;
    #pragma unroll 8
    for (int k = 0; k < EE; ++k) {
        const float w = Wih[(size_t)k * G4 + j];
        #pragma unroll
        for (int i = 0; i < 8; ++i) acc[i] += xs[i][k] * w;
    }
    #pragma unroll
    for (int i = 0; i < 8; ++i)
        Epre[(size_t)(mg * 8 + i) * G4 + j] = acc[i];
}

// ---------------------------------------------------------------------------
// Per-timestep attention kernel. One block per batch (32 blocks, 512 threads).
// Phase 0: LSTM pointwise for step t-1 (or zero-init)
// Phase 1: att2 = h @ W_dec_att (+bias), 2-way split-K
// Phase 2: e[p] = tanh(att1[p,:]+att2) @ W_full + b_full (8 waves over p)
// Phase 3: softmax over p
// Phase 4: context = alpha @ enc, 2-way split over p
// ---------------------------------------------------------------------------
__global__ void attn_step_kernel(int t,
                                 const float* __restrict__ att1,
                                 const float* __restrict__ enc,
                                 float* __restrict__ Hall,
                                 float* __restrict__ cbuf,
                                 const float* __restrict__ gates,
                                 float* __restrict__ context,
                                 const float* __restrict__ Wda,
                                 const float* __restrict__ bda,
                                 const float* __restrict__ Wfull,
                                 const float* __restrict__ bfull) {
    __shared__ float h_s[HH];
    __shared__ float part[2][256];
    __shared__ float att2_s[AA];
    __shared__ float e_s[256];
    __shared__ float red_s[256];
    const int b = blockIdx.x;
    const int tid = threadIdx.x;   // 0..511

    // Phase 0
    if (t == 0) {
        h_s[tid] = 0.f;
        cbuf[b * HH + tid] = 0.f;
    } else {
        const float* g = gates + b * G4;
        const float gi = g[tid];
        const float gf = g[HH + tid];
        const float gg = g[2 * HH + tid];
        const float go = g[3 * HH + tid];
        const float cp = cbuf[b * HH + tid];
        const float cn = fast_sigmoid(gf) * cp + fast_sigmoid(gi) * fast_tanh(gg);
        const float hn = fast_sigmoid(go) * fast_tanh(cn);
        cbuf[b * HH + tid] = cn;
        Hall[(size_t)(t - 1) * BH + b * HH + tid] = hn;
        h_s[tid] = hn;
    }
    __syncthreads();

    // Phase 1: att2, 2-way split-K (256 cols x 2 k-halves)
    {
        const int half = tid >> 8, col = tid & 255;
        const float* W = Wda + (size_t)(half * 256) * AA + col;
        const float* hh = h_s + half * 256;
        float acc = 0.f;
        #pragma unroll 8
        for (int k = 0; k < 256; ++k) acc += hh[k] * W[(size_t)k * AA];
        part[half][col] = acc;
    }
    __syncthreads();
    if (tid < 256) att2_s[tid] = part[0][tid] + part[1][tid] + bda[tid];
    __syncthreads();

    // Phase 2: e[p], one wave per p (8 waves)
    {
        const int wave = tid >> 6, lane = tid & 63;
        const float bf0 = bfull[0];
        for (int p = wave; p < PP; p += 8) {
            const float* row = att1 + ((size_t)b * PP + p) * AA;
            float s = 0.f;
            #pragma unroll
            for (int q = 0; q < 4; ++q) {
                const int a = lane + q * 64;
                s += fast_tanh(row[a] + att2_s[a]) * Wfull[a];
            }
            #pragma unroll
            for (int off = 32; off > 0; off >>= 1) s += __shfl_down(s, off, 64);
            if (lane == 0) e_s[p] = s + bf0;
        }
    }
    __syncthreads();

    // Phase 3: softmax (first 256 threads do the tree; all hit the syncs)
    const float val = (tid < PP) ? e_s[tid] : -3.4e38f;
    if (tid < 256) red_s[tid] = val;
    __syncthreads();
    #pragma unroll
    for (int s = 128; s > 0; s >>= 1) {
        if (tid < s) red_s[tid] = fmaxf(red_s[tid], red_s[tid + s]);
        __syncthreads();
    }
    const float mx = red_s[0];
    __syncthreads();
    const float ex = (tid < PP) ? __expf(val - mx) : 0.f;
    if (tid < 256) red_s[tid] = ex;
    __syncthreads();
    #pragma unroll
    for (int s = 128; s > 0; s >>= 1) {
        if (tid < s) red_s[tid] += red_s[tid + s];
        __syncthreads();
    }
    const float inv = 1.f / red_s[0];
    __syncthreads();
    if (tid < 256) e_s[tid] = ex * inv;   // alpha (0 for tid>=196)
    __syncthreads();

    // Phase 4: context, 2-way split over p (98 each)
    {
        const int half = tid >> 8, col = tid & 255;
        const float* erow = enc + (size_t)b * PP * DENC + col;
        float acc = 0.f;
        const int p0 = half * 98;
        #pragma unroll 7
        for (int p = p0; p < p0 + 98; ++p) acc += e_s[p] * erow[(size_t)p * DENC];
        part[half][col] = acc;
    }
    __syncthreads();
    if (tid < 256) context[b * DENC + tid] = part[0][tid] + part[1][tid];
}

// ---------------------------------------------------------------------------
// gates[b, j] = Epre[t*32+b, j] + context @ W_ih[512:768, j] + h @ W_hh[:, j]
// Grid (32 j-chunks of 64, 8 batch-groups of 4), 512 threads:
// 64 j x 4 b x 2 k-halves (split-K).
// ---------------------------------------------------------------------------
__global__ void gates_kernel(int t,
                             const float* __restrict__ context,
                             const float* __restrict__ Hall,
                             const float* __restrict__ Epre,
                             const float* __restrict__ Wih,
                             const float* __restrict__ Whh,
                             float* __restrict__ gates) {
    __shared__ float xs[4][768];
    __shared__ float part[2][256];
    const int tid = threadIdx.x;     // 0..511
    const int jc = blockIdx.x;       // 0..31
    const int bg = blockIdx.y;       // 0..7

    // Stage x = [context(256), h(512)] for 4 batches
    for (int idx = tid; idx < 4 * 768; idx += 512) {
        const int bi = idx / 768;
        const int k = idx - bi * 768;
        const int b = bg * 4 + bi;
        float v;
        if (k < 256) v = context[b * DENC + k];
        else v = (t > 0) ? Hall[(size_t)(t - 1) * BH + b * HH + (k - 256)] : 0.f;
        xs[bi][k] = v;
    }
    __syncthreads();

    const int khalf = tid >> 8;          // wave-uniform
    const int r = tid & 255;
    const int jl = r & 63, bl = r >> 6;
    const int j = jc * 64 + jl;
    const float* xrow = xs[bl];

    float acc = 0.f;
    if (khalf == 0) {
        // x[0:256] (context) * Wih rows 512..767, then x[256:384] * Whh rows 0..127
        const float* W1 = Wih + (size_t)512 * G4 + j;
        #pragma unroll 8
        for (int k = 0; k < 256; ++k) acc += xrow[k] * W1[(size_t)k * G4];
        const float* W2 = Whh + j;
        #pragma unroll 8
        for (int k = 0; k < 128; ++k) acc += xrow[256 + k] * W2[(size_t)k * G4];
    } else {
        // x[384:768] * Whh rows 128..511
        const float* W2 = Whh + (size_t)128 * G4 + j;
        #pragma unroll 8
        for (int k = 0; k < 384; ++k) acc += xrow[384 + k] * W2[(size_t)k * G4];
    }
    part[khalf][r] = acc;
    __syncthreads();

    if (tid < 256) {
        const int b = bg * 4 + bl;
        const float tot = part[0][tid] + part[1][tid]
                        + Epre[(size_t)(t * BB + b) * G4 + j];
        gates[(size_t)b * G4 + j] = tot;
    }
}

// ---------------------------------------------------------------------------
// LSTM pointwise update for the final step (t = T-1) -> Hall[T-1]
// ---------------------------------------------------------------------------
__global__ void final_update_kernel(const float* __restrict__ gates,
                                    const float* __restrict__ cbuf,
                                    float* __restrict__ Hall) {
    const int idx = blockIdx.x * 256 + threadIdx.x;   // < 16384
    const int b = idx >> 9, hi = idx & 511;
    const float* g = gates + b * G4;
    const float gi = g[hi];
    const float gf = g[HH + hi];
    const float gg = g[2 * HH + hi];
    const float go = g[3 * HH + hi];
    const float cp = cbuf[idx];
    const float cn = fast_sigmoid(gf) * cp + fast_sigmoid(gi) * fast_tanh(gg);
    const float hn = fast_sigmoid(go) * fast_tanh(cn);
    Hall[(size_t)(TT - 1) * BH + idx] = hn;
}

// ---------------------------------------------------------------------------
// Output projection: C[m, v] = Hall_flat[m,:] @ W_fc[:,v] + b_fc[v]
// m = t*32 + b, written to out[b][t][v].
// Tiled fp32 GEMM: BM=128, BN=128, BK=16, 256 threads, 8x8 micro-tile.
// ---------------------------------------------------------------------------
#define BM 128
#define BN 128
#define BK 16

__global__ void gemm_out(const float* __restrict__ Hall,
                         const float* __restrict__ Wfc,
                         const float* __restrict__ bfc,
                         float* __restrict__ out) {
    __shared__ float As[BM][BK + 1];
    __shared__ float Bs[BK][BN];
    const int tid = threadIdx.x;
    const int tx = tid & 15, ty = tid >> 4;
    const int m0 = blockIdx.y * BM;
    const int v0 = blockIdx.x * BN;

    const int ar = tid >> 2, akq = (tid & 3) * 4;     // A-tile: rows ar, ar+64
    const int bkr = tid >> 5, bnq = (tid & 31) * 4;   // B-tile: rows bkr, bkr+8

    float acc[8][8] = {};

    for (int k0 = 0; k0 < HH; k0 += BK) {
        #pragma unroll
        for (int h = 0; h < 2; ++h) {
            const int row = ar + h * 64;
            const float4 av = *reinterpret_cast<const float4*>(
                &Hall[(size_t)(m0 + row) * HH + k0 + akq]);
            As[row][akq + 0] = av.x; As[row][akq + 1] = av.y;
            As[row][akq + 2] = av.z; As[row][akq + 3] = av.w;
        }
        #pragma unroll
        for (int h = 0; h < 2; ++h) {
            const int kr = bkr + h * 8;
            const int vcol = v0 + bnq;
            float4 bv = {0.f, 0.f, 0.f, 0.f};
            if (vcol < VV)
                bv = *reinterpret_cast<const float4*>(
                    &Wfc[(size_t)(k0 + kr) * VV + vcol]);
            Bs[kr][bnq + 0] = bv.x; Bs[kr][bnq + 1] = bv.y;
            Bs[kr][bnq + 2] = bv.z; Bs[kr][bnq + 3] = bv.w;
        }
        __syncthreads();

        #pragma unroll
        for (int kk = 0; kk < BK; ++kk) {
            float a[8], bq[8];
            #pragma unroll
            for (int i = 0; i < 8; ++i) a[i] = As[ty * 8 + i][kk];
            #pragma unroll
            for (int jj = 0; jj < 8; ++jj) bq[jj] = Bs[kk][tx * 8 + jj];
            #pragma unroll
            for (int i = 0; i < 8; ++i)
                #pragma unroll
                for (int jj = 0; jj < 8; ++jj)
                    acc[i][jj] += a[i] * bq[jj];
        }
        __syncthreads();
    }

    #pragma unroll
    for (int i = 0; i < 8; ++i) {
        const int m = m0 + ty * 8 + i;
        const int t_idx = m >> 5;
        const int b_idx = m & 31;
        float* orow = out + ((size_t)b_idx * TT + t_idx) * VV;
        #pragma unroll
        for (int jj = 0; jj < 8; ++jj) {
            const int v = v0 + tx * 8 + jj;
            if (v < VV) orow[v] = acc[i][jj] + bfc[v];
        }
    }
}

// ---------------------------------------------------------------------------
extern "C" void kernel_launch(void* const* d_in, const int* in_sizes, int n_in,
                              void* d_out, int out_size, void* d_ws, size_t ws_size,
                              hipStream_t stream) {
    const float* enc      = (const float*)d_in[0];
    const int*   captions = (const int*)  d_in[1];
    const float* Wea      = (const float*)d_in[2];
    const float* bea      = (const float*)d_in[3];
    const float* Wda      = (const float*)d_in[4];
    const float* bda      = (const float*)d_in[5];
    const float* Wfull    = (const float*)d_in[6];
    const float* bfull    = (const float*)d_in[7];
    const float* emb      = (const float*)d_in[8];
    const float* Wih      = (const float*)d_in[9];
    const float* bih      = (const float*)d_in[10];
    const float* Whh      = (const float*)d_in[11];
    const float* bhh      = (const float*)d_in[12];
    const float* Wfc      = (const float*)d_in[13];
    const float* bfc      = (const float*)d_in[14];
    float* out = (float*)d_out;

    float* ws      = (float*)d_ws;
    float* att1    = ws;                        // 32*196*256     = 1,605,632
    float* Hall    = att1 + 1605632;            // 20*32*512      =   327,680
    float* cbuf    = Hall + 327680;             // 32*512         =    16,384
    float* context = cbuf + 16384;              // 32*256         =     8,192
    float* gates   = context + 8192;            // 32*2048        =    65,536
    float* Epre    = gates + 65536;             // 640*2048       = 1,310,720

    att1_kernel<<<dim3(784), dim3(256), 0, stream>>>(enc, Wea, bea, att1);
    epre_kernel<<<dim3(8, 80), dim3(256), 0, stream>>>(captions, emb, Wih, bih, bhh, Epre);

    for (int t = 0; t < TT; ++t) {
        attn_step_kernel<<<dim3(BB), dim3(512), 0, stream>>>(
            t, att1, enc, Hall, cbuf, gates, context, Wda, bda, Wfull, bfull);
        gates_kernel<<<dim3(32, 8), dim3(512), 0, stream>>>(
            t, context, Hall, Epre, Wih, Whh, gates);
    }
    final_update_kernel<<<dim3(64), dim3(256), 0, stream>>>(gates, cbuf, Hall);

    gemm_out<<<dim3((VV + BN - 1) / BN, (TT * BB) / BM), dim3(256), 0, stream>>>(
        Hall, Wfc, bfc, out);
}